// Round 1
// baseline (24134.166 us; speedup 1.0000x reference)
//
#include <hip/hip_runtime.h>
#include <hip/hip_bf16.h>
#include <math.h>

#define VOC 50257
#define NL 12
#define NH 12
#define DM 768
#define FF 3072
#define BB 2
#define TT 1024
#define HD 64
#define MR (BB*TT)   // 2048 rows

// ---------------- embedding: x = wte[idx] + wpe[t] ----------------
__global__ void embed_kernel(const int* __restrict__ idx, const float* __restrict__ wte,
                             const float* __restrict__ wpe, float* __restrict__ x) {
    int row = blockIdx.x;           // 0..MR-1, row = b*TT + t
    int t = row % TT;
    int tok = idx[row];
    for (int d = threadIdx.x; d < DM; d += blockDim.x)
        x[(size_t)row*DM + d] = wte[(size_t)tok*DM + d] + wpe[(size_t)t*DM + d];
}

// ---------------- layernorm: one wave (64 lanes) per row ----------------
__global__ void ln_kernel(const float* __restrict__ x, const float* __restrict__ g,
                          const float* __restrict__ b, float* __restrict__ out) {
    int row = blockIdx.x;
    int lane = threadIdx.x;  // 64
    const float* xr = x + (size_t)row*DM;
    float vals[DM/64];
    float s = 0.f;
    #pragma unroll
    for (int i = 0; i < DM/64; i++) { vals[i] = xr[lane + i*64]; s += vals[i]; }
    #pragma unroll
    for (int off = 32; off > 0; off >>= 1) s += __shfl_xor(s, off);
    float mean = s * (1.0f/DM);
    float vs = 0.f;
    #pragma unroll
    for (int i = 0; i < DM/64; i++) { float d = vals[i]-mean; vs += d*d; }
    #pragma unroll
    for (int off = 32; off > 0; off >>= 1) vs += __shfl_xor(vs, off);
    float rstd = rsqrtf(vs * (1.0f/DM) + 1e-5f);
    #pragma unroll
    for (int i = 0; i < DM/64; i++) {
        int d = lane + i*64;
        out[(size_t)row*DM + d] = (vals[i]-mean)*rstd*g[d] + b[d];
    }
}

// ---------------- f32 GEMM: C = act(A @ W + bias) (+ res) ----------------
// A [M,K] row-major, W [K,N] row-major. 64x64 tile, BK=16, 256 thr, 4x4/thr.
template<int GELU, int RES>
__global__ __launch_bounds__(256) void gemm_kernel(
        const float* __restrict__ A, const float* __restrict__ W,
        const float* __restrict__ bias, const float* __restrict__ res,
        float* __restrict__ C, int M, int N, int K) {
    __shared__ float As[16][68];   // [kk][m], padded to 68 (16B-aligned rows)
    __shared__ float Ws[16][64];   // [kk][n]
    int tid = threadIdx.x;
    int tx = tid & 15, ty = tid >> 4;
    int m0 = blockIdx.y * 64, n0 = blockIdx.x * 64;
    float acc[4][4] = {};
    for (int k0 = 0; k0 < K; k0 += 16) {
        #pragma unroll
        for (int i = tid; i < 64*16; i += 256) {
            int r = i >> 4, c = i & 15;                     // r: m-row, c: k-col
            As[c][r] = A[(size_t)(m0 + r)*K + k0 + c];      // M,K always tile-divisible
        }
        #pragma unroll
        for (int i = tid; i < 16*64; i += 256) {
            int r = i >> 6, c = i & 63;                     // r: k-row, c: n-col
            int n = n0 + c;
            Ws[r][c] = (n < N) ? W[(size_t)(k0 + r)*N + n] : 0.f;
        }
        __syncthreads();
        #pragma unroll
        for (int kk = 0; kk < 16; kk++) {
            float a[4], w[4];
            #pragma unroll
            for (int i = 0; i < 4; i++) a[i] = As[kk][ty*4+i];
            #pragma unroll
            for (int j = 0; j < 4; j++) w[j] = Ws[kk][tx*4+j];
            #pragma unroll
            for (int i = 0; i < 4; i++)
                #pragma unroll
                for (int j = 0; j < 4; j++)
                    acc[i][j] += a[i]*w[j];
        }
        __syncthreads();
    }
    #pragma unroll
    for (int i = 0; i < 4; i++) {
        int m = m0 + ty*4 + i;
        #pragma unroll
        for (int j = 0; j < 4; j++) {
            int n = n0 + tx*4 + j;
            if (n >= N) continue;
            float v = acc[i][j];
            if (bias) v += bias[n];
            if (GELU) {
                float xx = v;
                v = 0.5f*xx*(1.f + tanhf(0.7978845608028654f*(xx + 0.047715f*xx*xx*xx)));
            }
            if (RES) v += res[(size_t)m*N + n];
            C[(size_t)m*N + n] = v;
        }
    }
}

// ---------------- causal attention: one wave per (b,h,q) ----------------
// qkv [MR][3*DM]; y [MR][DM]
__global__ __launch_bounds__(64) void attn_kernel(const float* __restrict__ qkv,
                                                  float* __restrict__ y) {
    int bid = blockIdx.x;          // b*NH*TT + h*TT + q
    int q = bid % TT;
    int h = (bid / TT) % NH;
    int b = bid / (TT * NH);
    int lane = threadIdx.x;
    __shared__ float qs[64];
    __shared__ float os[64][65];
    __shared__ float ssum[64];
    const float scale = 0.125f;    // 1/sqrt(64)
    const float* qptr = qkv + ((size_t)(b*TT + q))*3*DM + h*64;
    qs[lane] = qptr[lane];
    __syncthreads();
    float m = -INFINITY, s = 0.f;
    float acc[64];
    #pragma unroll
    for (int d = 0; d < 64; d++) acc[d] = 0.f;
    for (int k = lane; k <= q; k += 64) {
        const float* kptr = qkv + ((size_t)(b*TT + k))*3*DM + DM + h*64;
        const float* vptr = kptr + DM;
        float dot = 0.f;
        #pragma unroll
        for (int d = 0; d < 64; d++) dot += qs[d]*kptr[d];
        dot *= scale;
        if (dot <= m) {
            float p = expf(dot - m);
            s += p;
            #pragma unroll
            for (int d = 0; d < 64; d++) acc[d] += p*vptr[d];
        } else {
            float corr = (m == -INFINITY) ? 0.f : expf(m - dot);
            s = s*corr + 1.f;
            #pragma unroll
            for (int d = 0; d < 64; d++) acc[d] = acc[d]*corr + vptr[d];
            m = dot;
        }
    }
    // cross-lane combine
    float M = m;
    #pragma unroll
    for (int off = 32; off > 0; off >>= 1) M = fmaxf(M, __shfl_xor(M, off));
    float sc = (m == -INFINITY) ? 0.f : expf(m - M);
    float S = s * sc;
    #pragma unroll
    for (int off = 32; off > 0; off >>= 1) S += __shfl_xor(S, off);
    #pragma unroll
    for (int d = 0; d < 64; d++) os[lane][d] = acc[d]*sc;
    ssum[lane] = S;
    __syncthreads();
    float sum = 0.f;
    #pragma unroll
    for (int l = 0; l < 64; l++) sum += os[l][lane];   // lane == output dim d
    y[((size_t)(b*TT + q))*DM + h*64 + lane] = sum / ssum[0];
}

// ---------------- loss ----------------
__global__ void zero_acc_kernel(float* p) { p[threadIdx.x] = 0.f; }

__global__ __launch_bounds__(256) void loss_kernel(const float* __restrict__ logits,
                                                   const int* __restrict__ targets,
                                                   float* __restrict__ acc) {
    int row = blockIdx.x;
    int tid = threadIdx.x;
    __shared__ float red[256];
    const float* lr = logits + (size_t)row * VOC;
    float mx = -INFINITY;
    for (int c = tid; c < VOC; c += 256) mx = fmaxf(mx, lr[c]);
    red[tid] = mx; __syncthreads();
    for (int off = 128; off > 0; off >>= 1) {
        if (tid < off) red[tid] = fmaxf(red[tid], red[tid+off]);
        __syncthreads();
    }
    mx = red[0]; __syncthreads();
    float se = 0.f;
    for (int c = tid; c < VOC; c += 256) se += expf(lr[c] - mx);
    red[tid] = se; __syncthreads();
    for (int off = 128; off > 0; off >>= 1) {
        if (tid < off) red[tid] += red[tid+off];
        __syncthreads();
    }
    if (tid == 0) {
        int tgt = targets[row];
        if (tgt >= 0) {
            float lse = logf(red[0]) + mx;
            atomicAdd(&acc[0], lse - lr[tgt]);
            atomicAdd(&acc[1], 1.f);
        }
    }
}

__global__ void loss_final_kernel(const float* acc, float* out) {
    out[0] = acc[0] / acc[1];
}

// ---------------- launch ----------------
extern "C" void kernel_launch(void* const* d_in, const int* in_sizes, int n_in,
                              void* d_out, int out_size, void* d_ws, size_t ws_size,
                              hipStream_t stream) {
    const int*   idx     = (const int*)  d_in[0];
    const int*   targets = (const int*)  d_in[1];
    const float* wte     = (const float*)d_in[2];
    const float* wpe     = (const float*)d_in[3];
    const float* ln1_g   = (const float*)d_in[4];
    const float* ln1_b   = (const float*)d_in[5];
    const float* qkv_w   = (const float*)d_in[6];
    const float* qkv_b   = (const float*)d_in[7];
    const float* po_w    = (const float*)d_in[8];
    const float* po_b    = (const float*)d_in[9];
    const float* ln2_g   = (const float*)d_in[10];
    const float* ln2_b   = (const float*)d_in[11];
    const float* fc_w    = (const float*)d_in[12];
    const float* fc_b    = (const float*)d_in[13];
    const float* pr_w    = (const float*)d_in[14];
    const float* pr_b    = (const float*)d_in[15];
    const float* lnf_g   = (const float*)d_in[16];
    const float* lnf_b   = (const float*)d_in[17];
    const float* lm_w    = (const float*)d_in[18];

    float* logits = (float*)d_out;                 // [MR][VOC] then loss at end
    float* ws = (float*)d_ws;
    float* x    = ws;                              // [MR][DM]
    float* h    = x    + (size_t)MR*DM;            // [MR][DM]
    float* qkvb = h    + (size_t)MR*DM;            // [MR][3*DM]
    float* yb   = qkvb + (size_t)MR*3*DM;          // [MR][DM]
    float* fb   = yb   + (size_t)MR*DM;            // [MR][FF]
    float* lacc = fb   + (size_t)MR*FF;            // [2]

    embed_kernel<<<MR, 256, 0, stream>>>(idx, wte, wpe, x);

    for (int l = 0; l < NL; l++) {
        // h = LN(x)
        ln_kernel<<<MR, 64, 0, stream>>>(x, ln1_g + l*DM, ln1_b + l*DM, h);
        // qkv = h @ Wqkv + b
        gemm_kernel<0,0><<<dim3((3*DM)/64, MR/64), 256, 0, stream>>>(
            h, qkv_w + (size_t)l*DM*3*DM, qkv_b + (size_t)l*3*DM, nullptr,
            qkvb, MR, 3*DM, DM);
        // y = attention(qkv)
        attn_kernel<<<BB*NH*TT, 64, 0, stream>>>(qkvb, yb);
        // x = x + y @ Wo + bo
        gemm_kernel<0,1><<<dim3(DM/64, MR/64), 256, 0, stream>>>(
            yb, po_w + (size_t)l*DM*DM, po_b + (size_t)l*DM, x,
            x, MR, DM, DM);
        // h = LN(x)
        ln_kernel<<<MR, 64, 0, stream>>>(x, ln2_g + l*DM, ln2_b + l*DM, h);
        // f = gelu(h @ Wf + bf)
        gemm_kernel<1,0><<<dim3(FF/64, MR/64), 256, 0, stream>>>(
            h, fc_w + (size_t)l*DM*FF, fc_b + (size_t)l*FF, nullptr,
            fb, MR, FF, DM);
        // x = x + f @ Wp + bp
        gemm_kernel<0,1><<<dim3(DM/64, MR/64), 256, 0, stream>>>(
            fb, pr_w + (size_t)l*FF*DM, pr_b + (size_t)l*DM, x,
            x, MR, DM, FF);
    }

    // final LN + LM head
    ln_kernel<<<MR, 64, 0, stream>>>(x, lnf_g, lnf_b, h);
    gemm_kernel<0,0><<<dim3((VOC + 63)/64, MR/64), 256, 0, stream>>>(
        h, lm_w, nullptr, nullptr, logits, MR, VOC, DM);

    // loss
    zero_acc_kernel<<<1, 2, 0, stream>>>(lacc);
    loss_kernel<<<MR, 256, 0, stream>>>(logits, targets, lacc);
    loss_final_kernel<<<1, 1, 0, stream>>>(lacc, logits + (size_t)MR*VOC);
}

// Round 2
// 11521.377 us; speedup vs baseline: 2.0947x; 2.0947x over previous
//
#include <hip/hip_runtime.h>
#include <hip/hip_bf16.h>
#include <math.h>

#define VOC 50257
#define NL 12
#define NH 12
#define DM 768
#define FF 3072
#define BB 2
#define TT 1024
#define MR (BB*TT)   // 2048 rows

typedef __attribute__((ext_vector_type(8))) short bf16x8;
typedef __attribute__((ext_vector_type(4))) float f32x4;

__device__ __forceinline__ float mgelu_f(float x) {
    return 0.5f*x*(1.f + tanhf(0.7978845608028654f*(x + 0.047715f*x*x*x)));
}

// ---------------- embedding: x = wte[idx] + wpe[t] (f32) ----------------
__global__ void embed_kernel(const int* __restrict__ idx, const float* __restrict__ wte,
                             const float* __restrict__ wpe, float* __restrict__ x) {
    int row = blockIdx.x;
    int t = row % TT;
    int tok = idx[row];
    for (int d = threadIdx.x; d < DM; d += blockDim.x)
        x[(size_t)row*DM + d] = wte[(size_t)tok*DM + d] + wpe[(size_t)t*DM + d];
}

// ---------------- layernorm: f32 in -> bf16 out, one wave per row ----------------
__global__ void ln_kernel(const float* __restrict__ x, const float* __restrict__ g,
                          const float* __restrict__ b, __hip_bfloat16* __restrict__ out) {
    int row = blockIdx.x;
    int lane = threadIdx.x;  // 64
    const float* xr = x + (size_t)row*DM;
    float vals[DM/64];
    float s = 0.f;
    #pragma unroll
    for (int i = 0; i < DM/64; i++) { vals[i] = xr[lane + i*64]; s += vals[i]; }
    #pragma unroll
    for (int off = 32; off > 0; off >>= 1) s += __shfl_xor(s, off);
    float mean = s * (1.0f/DM);
    float vs = 0.f;
    #pragma unroll
    for (int i = 0; i < DM/64; i++) { float d = vals[i]-mean; vs += d*d; }
    #pragma unroll
    for (int off = 32; off > 0; off >>= 1) vs += __shfl_xor(vs, off);
    float rstd = rsqrtf(vs * (1.0f/DM) + 1e-5f);
    #pragma unroll
    for (int i = 0; i < DM/64; i++) {
        int d = lane + i*64;
        out[(size_t)row*DM + d] = __float2bfloat16((vals[i]-mean)*rstd*g[d] + b[d]);
    }
}

// ---------------- transpose + f32->bf16: in [R][C] -> out [C][R] ----------------
__global__ void transpose_cvt_kernel(const float* __restrict__ in, __hip_bfloat16* __restrict__ out,
                                     int R, int C) {
    __shared__ float tile[32][33];
    int c0 = blockIdx.x*32, r0 = blockIdx.y*32;
    int tx = threadIdx.x, ty = threadIdx.y;   // 32 x 8
    #pragma unroll
    for (int i = ty; i < 32; i += 8) {
        int r = r0 + i, c = c0 + tx;
        tile[i][tx] = (r < R && c < C) ? in[(size_t)r*C + c] : 0.f;
    }
    __syncthreads();
    #pragma unroll
    for (int i = ty; i < 32; i += 8) {
        int c = c0 + i, r = r0 + tx;
        if (c < C && r < R) out[(size_t)c*R + r] = __float2bfloat16(tile[tx][i]);
    }
}

// ---------------- MFMA bf16 GEMM: C = epi(A @ Wt^T + bias) ----------------
// A [M][K] bf16 row-major, Wt [N][K] bf16 row-major (pre-transposed weight).
// 128x128 tile, BK=32, 256 threads (4 waves, 2x2), 4x4 fragments of 16x16x32.
// LDS layout k-quad-major: [kq(4)][row(128)][8 bf16] -> conflict-free b128 reads.
// MODE: 0 = f32 out (no bias), 1 = bf16 out +bias, 2 = f32 out +bias+res, 3 = bf16 gelu(+bias)
template<int MODE>
__global__ __launch_bounds__(256) void mfma_gemm_kernel(
        const __hip_bfloat16* __restrict__ A,
        const __hip_bfloat16* __restrict__ Wt,
        const float* __restrict__ bias,
        const float* __restrict__ res,
        void* __restrict__ Cout,
        int M, int N, int K) {
    __shared__ __align__(16) char As[8192];   // [4][128][8] bf16
    __shared__ __align__(16) char Bs[8192];
    int tid = threadIdx.x;
    int lane = tid & 63, wid = tid >> 6;
    int wm = wid >> 1, wn = wid & 1;
    int m0 = blockIdx.y * 128, n0 = blockIdx.x * 128;
    int kq = lane >> 4, lr = lane & 15;

    f32x4 acc[4][4] = {};

    for (int k0 = 0; k0 < K; k0 += 32) {
        // ---- stage A,B tiles: each wave issues 2 A-loads + 2 B-loads (1KB each)
        #pragma unroll
        for (int t = 0; t < 2; t++) {
            int lx = wid + t*4;                 // 0..7
            int r  = (lx & 1)*64 + lane;        // tile row
            int kk = (lx >> 1)*8;               // k offset within BK
            const __hip_bfloat16* ga = A + (size_t)(m0 + r)*K + k0 + kk;
            __builtin_amdgcn_global_load_lds(
                (const __attribute__((address_space(1))) void*)ga,
                (__attribute__((address_space(3))) void*)(As + lx*1024), 16, 0, 0);
            int nr = n0 + r; if (nr > N-1) nr = N-1;   // clamp for ragged N
            const __hip_bfloat16* gb = Wt + (size_t)nr*K + k0 + kk;
            __builtin_amdgcn_global_load_lds(
                (const __attribute__((address_space(1))) void*)gb,
                (__attribute__((address_space(3))) void*)(Bs + lx*1024), 16, 0, 0);
        }
        __syncthreads();

        // ---- fragments + 16 MFMA
        bf16x8 afrag[4], bfrag[4];
        #pragma unroll
        for (int m = 0; m < 4; m++)
            afrag[m] = *(const bf16x8*)(As + kq*2048 + (wm*64 + m*16 + lr)*16);
        #pragma unroll
        for (int n = 0; n < 4; n++)
            bfrag[n] = *(const bf16x8*)(Bs + kq*2048 + (wn*64 + n*16 + lr)*16);
        #pragma unroll
        for (int m = 0; m < 4; m++)
            #pragma unroll
            for (int n = 0; n < 4; n++)
                acc[m][n] = __builtin_amdgcn_mfma_f32_16x16x32_bf16(afrag[m], bfrag[n], acc[m][n], 0, 0, 0);
        __syncthreads();
    }

    // ---- epilogue: C/D layout col=lane&15, row=(lane>>4)*4+reg
    #pragma unroll
    for (int m = 0; m < 4; m++) {
        #pragma unroll
        for (int n = 0; n < 4; n++) {
            int col = n0 + wn*64 + n*16 + lr;
            if (col >= N) continue;
            float bv = (MODE == 0) ? 0.f : bias[col];
            #pragma unroll
            for (int j = 0; j < 4; j++) {
                int row = m0 + wm*64 + m*16 + kq*4 + j;
                float v = acc[m][n][j] + bv;
                size_t o = (size_t)row*N + col;
                if (MODE == 0) {
                    ((float*)Cout)[o] = v;
                } else if (MODE == 1) {
                    ((__hip_bfloat16*)Cout)[o] = __float2bfloat16(v);
                } else if (MODE == 2) {
                    ((float*)Cout)[o] = v + res[o];
                } else {
                    ((__hip_bfloat16*)Cout)[o] = __float2bfloat16(mgelu_f(v));
                }
            }
        }
    }
}

// ---------------- causal attention: one wave per (b,h,q), bf16 I/O ----------------
__global__ __launch_bounds__(64) void attn_kernel(const __hip_bfloat16* __restrict__ qkv,
                                                  __hip_bfloat16* __restrict__ y) {
    int bid = blockIdx.x;          // b*NH*TT + h*TT + q
    int q = bid % TT;
    int h = (bid / TT) % NH;
    int b = bid / (TT * NH);
    int lane = threadIdx.x;
    __shared__ float qs[64];
    __shared__ float os[64][65];
    __shared__ float ssum[64];
    const float scale = 0.125f;    // 1/sqrt(64)
    const __hip_bfloat16* qptr = qkv + ((size_t)(b*TT + q))*3*DM + h*64;
    qs[lane] = __bfloat162float(qptr[lane]);
    __syncthreads();
    float m = -INFINITY, s = 0.f;
    float acc[64];
    #pragma unroll
    for (int d = 0; d < 64; d++) acc[d] = 0.f;
    for (int k = lane; k <= q; k += 64) {
        const __hip_bfloat16* kptr = qkv + ((size_t)(b*TT + k))*3*DM + DM + h*64;
        const __hip_bfloat16* vptr = kptr + DM;
        float dot = 0.f;
        #pragma unroll
        for (int c = 0; c < 8; c++) {
            uint4 k4 = *(const uint4*)(kptr + c*8);
            const ushort* ku = (const ushort*)&k4;
            #pragma unroll
            for (int i = 0; i < 8; i++)
                dot += qs[c*8+i] * __uint_as_float(((unsigned)ku[i]) << 16);
        }
        dot *= scale;
        float p, corr;
        if (dot <= m) { p = expf(dot - m); corr = 1.f; s += p; }
        else { corr = (m == -INFINITY) ? 0.f : expf(m - dot); s = s*corr + 1.f; p = 1.f; m = dot; }
        #pragma unroll
        for (int c = 0; c < 8; c++) {
            uint4 v4 = *(const uint4*)(vptr + c*8);
            const ushort* vu = (const ushort*)&v4;
            #pragma unroll
            for (int i = 0; i < 8; i++)
                acc[c*8+i] = acc[c*8+i]*corr + p*__uint_as_float(((unsigned)vu[i]) << 16);
        }
    }
    // cross-lane combine
    float M = m;
    #pragma unroll
    for (int off = 32; off > 0; off >>= 1) M = fmaxf(M, __shfl_xor(M, off));
    float sc = (m == -INFINITY) ? 0.f : expf(m - M);
    float S = s * sc;
    #pragma unroll
    for (int off = 32; off > 0; off >>= 1) S += __shfl_xor(S, off);
    #pragma unroll
    for (int d = 0; d < 64; d++) os[lane][d] = acc[d]*sc;
    ssum[lane] = S;
    __syncthreads();
    float sum = 0.f;
    #pragma unroll
    for (int l = 0; l < 64; l++) sum += os[l][lane];
    y[((size_t)(b*TT + q))*DM + h*64 + lane] = __float2bfloat16(sum / ssum[0]);
}

// ---------------- loss ----------------
__global__ void zero_acc_kernel(float* p) { p[threadIdx.x] = 0.f; }

__global__ __launch_bounds__(256) void loss_kernel(const float* __restrict__ logits,
                                                   const int* __restrict__ targets,
                                                   float* __restrict__ acc) {
    int row = blockIdx.x;
    int tid = threadIdx.x;
    __shared__ float red[256];
    const float* lr = logits + (size_t)row * VOC;
    float mx = -INFINITY;
    for (int c = tid; c < VOC; c += 256) mx = fmaxf(mx, lr[c]);
    red[tid] = mx; __syncthreads();
    for (int off = 128; off > 0; off >>= 1) {
        if (tid < off) red[tid] = fmaxf(red[tid], red[tid+off]);
        __syncthreads();
    }
    mx = red[0]; __syncthreads();
    float se = 0.f;
    for (int c = tid; c < VOC; c += 256) se += expf(lr[c] - mx);
    red[tid] = se; __syncthreads();
    for (int off = 128; off > 0; off >>= 1) {
        if (tid < off) red[tid] += red[tid+off];
        __syncthreads();
    }
    if (tid == 0) {
        int tgt = targets[row];
        if (tgt >= 0) {
            float lse = logf(red[0]) + mx;
            atomicAdd(&acc[0], lse - lr[tgt]);
            atomicAdd(&acc[1], 1.f);
        }
    }
}

__global__ void loss_final_kernel(const float* acc, float* out) {
    out[0] = acc[0] / acc[1];
}

// ---------------- launch ----------------
extern "C" void kernel_launch(void* const* d_in, const int* in_sizes, int n_in,
                              void* d_out, int out_size, void* d_ws, size_t ws_size,
                              hipStream_t stream) {
    const int*   idx     = (const int*)  d_in[0];
    const int*   targets = (const int*)  d_in[1];
    const float* wte     = (const float*)d_in[2];
    const float* wpe     = (const float*)d_in[3];
    const float* ln1_g   = (const float*)d_in[4];
    const float* ln1_b   = (const float*)d_in[5];
    const float* qkv_w   = (const float*)d_in[6];
    const float* qkv_b   = (const float*)d_in[7];
    const float* po_w    = (const float*)d_in[8];
    const float* po_b    = (const float*)d_in[9];
    const float* ln2_g   = (const float*)d_in[10];
    const float* ln2_b   = (const float*)d_in[11];
    const float* fc_w    = (const float*)d_in[12];
    const float* fc_b    = (const float*)d_in[13];
    const float* pr_w    = (const float*)d_in[14];
    const float* pr_b    = (const float*)d_in[15];
    const float* lnf_g   = (const float*)d_in[16];
    const float* lnf_b   = (const float*)d_in[17];
    const float* lm_w    = (const float*)d_in[18];

    float* logits = (float*)d_out;                 // [MR][VOC], loss appended

    char* p = (char*)d_ws;
    float* x = (float*)p;                 p += (size_t)MR*DM*4;
    __hip_bfloat16* h    = (__hip_bfloat16*)p; p += (size_t)MR*DM*2;
    __hip_bfloat16* qkvb = (__hip_bfloat16*)p; p += (size_t)MR*3*DM*2;
    __hip_bfloat16* yb   = (__hip_bfloat16*)p; p += (size_t)MR*DM*2;
    __hip_bfloat16* fb   = (__hip_bfloat16*)p; p += (size_t)MR*FF*2;
    __hip_bfloat16* lm_wt  = (__hip_bfloat16*)p; p += (size_t)VOC*DM*2;
    __hip_bfloat16* qkv_wt = (__hip_bfloat16*)p; p += (size_t)3*DM*DM*2;
    __hip_bfloat16* po_wt  = (__hip_bfloat16*)p; p += (size_t)DM*DM*2;
    __hip_bfloat16* fc_wt  = (__hip_bfloat16*)p; p += (size_t)FF*DM*2;
    __hip_bfloat16* pr_wt  = (__hip_bfloat16*)p; p += (size_t)DM*FF*2;
    float* lacc = (float*)p;

    dim3 tpb(32, 8);

    embed_kernel<<<MR, 256, 0, stream>>>(idx, wte, wpe, x);

    // LM-head weight: [768][50257] -> bf16 [50257][768] (once)
    transpose_cvt_kernel<<<dim3((VOC+31)/32, (DM+31)/32), tpb, 0, stream>>>(lm_w, lm_wt, DM, VOC);

    for (int l = 0; l < NL; l++) {
        // per-layer weight transposes (buffers reused; stream-ordered)
        transpose_cvt_kernel<<<dim3((3*DM+31)/32, (DM+31)/32), tpb, 0, stream>>>(
            qkv_w + (size_t)l*DM*3*DM, qkv_wt, DM, 3*DM);
        transpose_cvt_kernel<<<dim3((DM+31)/32, (DM+31)/32), tpb, 0, stream>>>(
            po_w + (size_t)l*DM*DM, po_wt, DM, DM);
        transpose_cvt_kernel<<<dim3((FF+31)/32, (DM+31)/32), tpb, 0, stream>>>(
            fc_w + (size_t)l*DM*FF, fc_wt, DM, FF);
        transpose_cvt_kernel<<<dim3((DM+31)/32, (FF+31)/32), tpb, 0, stream>>>(
            pr_w + (size_t)l*FF*DM, pr_wt, FF, DM);

        // h = LN(x)  [bf16]
        ln_kernel<<<MR, 64, 0, stream>>>(x, ln1_g + l*DM, ln1_b + l*DM, h);
        // qkv = h @ Wqkv + b  [bf16]
        mfma_gemm_kernel<1><<<dim3(3*DM/128, MR/128), 256, 0, stream>>>(
            h, qkv_wt, qkv_b + (size_t)l*3*DM, nullptr, qkvb, MR, 3*DM, DM);
        // y = attention(qkv)  [bf16]
        attn_kernel<<<BB*NH*TT, 64, 0, stream>>>(qkvb, yb);
        // x = x + y @ Wo + bo  [f32]
        mfma_gemm_kernel<2><<<dim3(DM/128, MR/128), 256, 0, stream>>>(
            yb, po_wt, po_b + (size_t)l*DM, x, x, MR, DM, DM);
        // h = LN(x)  [bf16]
        ln_kernel<<<MR, 64, 0, stream>>>(x, ln2_g + l*DM, ln2_b + l*DM, h);
        // f = gelu(h @ Wf + bf)  [bf16]
        mfma_gemm_kernel<3><<<dim3(FF/128, MR/128), 256, 0, stream>>>(
            h, fc_wt, fc_b + (size_t)l*FF, nullptr, fb, MR, FF, DM);
        // x = x + f @ Wp + bp  [f32]
        mfma_gemm_kernel<2><<<dim3(DM/128, MR/128), 256, 0, stream>>>(
            fb, pr_wt, pr_b + (size_t)l*DM, x, x, MR, DM, FF);
    }

    // final LN + LM head
    ln_kernel<<<MR, 64, 0, stream>>>(x, lnf_g, lnf_b, h);
    mfma_gemm_kernel<0><<<dim3((VOC+127)/128, MR/128), 256, 0, stream>>>(
        h, lm_wt, nullptr, nullptr, logits, MR, VOC, DM);

    // loss
    zero_acc_kernel<<<1, 2, 0, stream>>>(lacc);
    loss_kernel<<<MR, 256, 0, stream>>>(logits, targets, lacc);
    loss_final_kernel<<<1, 1, 0, stream>>>(lacc, logits + (size_t)MR*VOC);
}

// Round 4
// 3971.255 us; speedup vs baseline: 6.0772x; 2.9012x over previous
//
#include <hip/hip_runtime.h>
#include <hip/hip_bf16.h>
#include <math.h>

#define VOC 50257
#define NL 12
#define NH 12
#define DM 768
#define FF 3072
#define BB 2
#define TT 1024
#define MR (BB*TT)   // 2048 rows

typedef __attribute__((ext_vector_type(8))) short bf16x8;
typedef __attribute__((ext_vector_type(4))) float f32x4;

__device__ __forceinline__ float mgelu_f(float x) {
    return 0.5f*x*(1.f + tanhf(0.7978845608028654f*(x + 0.047715f*x*x*x)));
}

__device__ __forceinline__ unsigned short f2bf(float f) {
    __hip_bfloat16 h = __float2bfloat16(f);
    return *reinterpret_cast<unsigned short*>(&h);
}

// ---------------- embedding: x = wte[idx] + wpe[t] (f32) ----------------
__global__ void embed_kernel(const int* __restrict__ idx, const float* __restrict__ wte,
                             const float* __restrict__ wpe, float* __restrict__ x) {
    int row = blockIdx.x;
    int t = row % TT;
    int tok = idx[row];
    for (int d = threadIdx.x; d < DM; d += blockDim.x)
        x[(size_t)row*DM + d] = wte[(size_t)tok*DM + d] + wpe[(size_t)t*DM + d];
}

// ---------------- layernorm: f32 in -> bf16 out, one wave per row ----------------
__global__ void ln_kernel(const float* __restrict__ x, const float* __restrict__ g,
                          const float* __restrict__ b, __hip_bfloat16* __restrict__ out) {
    int row = blockIdx.x;
    int lane = threadIdx.x;  // 64
    const float* xr = x + (size_t)row*DM;
    float vals[DM/64];
    float s = 0.f;
    #pragma unroll
    for (int i = 0; i < DM/64; i++) { vals[i] = xr[lane + i*64]; s += vals[i]; }
    #pragma unroll
    for (int off = 32; off > 0; off >>= 1) s += __shfl_xor(s, off);
    float mean = s * (1.0f/DM);
    float vs = 0.f;
    #pragma unroll
    for (int i = 0; i < DM/64; i++) { float d = vals[i]-mean; vs += d*d; }
    #pragma unroll
    for (int off = 32; off > 0; off >>= 1) vs += __shfl_xor(vs, off);
    float rstd = rsqrtf(vs * (1.0f/DM) + 1e-5f);
    #pragma unroll
    for (int i = 0; i < DM/64; i++) {
        int d = lane + i*64;
        out[(size_t)row*DM + d] = __float2bfloat16((vals[i]-mean)*rstd*g[d] + b[d]);
    }
}

// ---------------- transpose + f32->bf16: in [R][C] -> out [C][R] ----------------
__global__ void transpose_cvt_kernel(const float* __restrict__ in, __hip_bfloat16* __restrict__ out,
                                     int R, int C) {
    __shared__ float tile[32][33];
    int c0 = blockIdx.x*32, r0 = blockIdx.y*32;
    int tx = threadIdx.x, ty = threadIdx.y;   // 32 x 8
    #pragma unroll
    for (int i = ty; i < 32; i += 8) {
        int r = r0 + i, c = c0 + tx;
        tile[i][tx] = (r < R && c < C) ? in[(size_t)r*C + c] : 0.f;
    }
    __syncthreads();
    #pragma unroll
    for (int i = ty; i < 32; i += 8) {
        int c = c0 + i, r = r0 + tx;
        if (c < C && r < R) out[(size_t)c*R + r] = __float2bfloat16(tile[tx][i]);
    }
}

// ---------------- MFMA bf16 GEMM: C = epi(A @ Wt^T + bias) ----------------
// MODE: 0 = f32 out (no bias), 1 = bf16 out +bias (+V^T side-write for attention),
//       2 = f32 out +bias+res, 3 = bf16 gelu(+bias)
template<int MODE>
__global__ __launch_bounds__(256) void mfma_gemm_kernel(
        const __hip_bfloat16* __restrict__ A,
        const __hip_bfloat16* __restrict__ Wt,
        const float* __restrict__ bias,
        const float* __restrict__ res,
        void* __restrict__ Cout,
        __hip_bfloat16* __restrict__ vt,
        int M, int N, int K) {
    __shared__ __align__(16) char As[8192];   // [4][128][8] bf16
    __shared__ __align__(16) char Bs[8192];
    int tid = threadIdx.x;
    int lane = tid & 63, wid = tid >> 6;
    int wm = wid >> 1, wn = wid & 1;
    int m0 = blockIdx.y * 128, n0 = blockIdx.x * 128;
    int kq = lane >> 4, lr = lane & 15;

    f32x4 acc[4][4] = {};

    for (int k0 = 0; k0 < K; k0 += 32) {
        #pragma unroll
        for (int t = 0; t < 2; t++) {
            int lx = wid + t*4;                 // 0..7
            int r  = (lx & 1)*64 + lane;        // tile row
            int kk = (lx >> 1)*8;               // k offset within BK
            const __hip_bfloat16* ga = A + (size_t)(m0 + r)*K + k0 + kk;
            __builtin_amdgcn_global_load_lds(
                (const __attribute__((address_space(1))) void*)ga,
                (__attribute__((address_space(3))) void*)(As + lx*1024), 16, 0, 0);
            int nr = n0 + r; if (nr > N-1) nr = N-1;   // clamp for ragged N
            const __hip_bfloat16* gb = Wt + (size_t)nr*K + k0 + kk;
            __builtin_amdgcn_global_load_lds(
                (const __attribute__((address_space(1))) void*)gb,
                (__attribute__((address_space(3))) void*)(Bs + lx*1024), 16, 0, 0);
        }
        __syncthreads();

        bf16x8 afrag[4], bfrag[4];
        #pragma unroll
        for (int m = 0; m < 4; m++)
            afrag[m] = *(const bf16x8*)(As + kq*2048 + (wm*64 + m*16 + lr)*16);
        #pragma unroll
        for (int n = 0; n < 4; n++)
            bfrag[n] = *(const bf16x8*)(Bs + kq*2048 + (wn*64 + n*16 + lr)*16);
        #pragma unroll
        for (int m = 0; m < 4; m++)
            #pragma unroll
            for (int n = 0; n < 4; n++)
                acc[m][n] = __builtin_amdgcn_mfma_f32_16x16x32_bf16(afrag[m], bfrag[n], acc[m][n], 0, 0, 0);
        __syncthreads();
    }

    #pragma unroll
    for (int m = 0; m < 4; m++) {
        #pragma unroll
        for (int n = 0; n < 4; n++) {
            int col = n0 + wn*64 + n*16 + lr;
            if (col >= N) continue;
            float bv = (MODE == 0) ? 0.f : bias[col];
            #pragma unroll
            for (int j = 0; j < 4; j++) {
                int row = m0 + wm*64 + m*16 + kq*4 + j;
                float v = acc[m][n][j] + bv;
                size_t o = (size_t)row*N + col;
                if (MODE == 0) {
                    ((float*)Cout)[o] = v;
                } else if (MODE == 1) {
                    __hip_bfloat16 bvv = __float2bfloat16(v);
                    ((__hip_bfloat16*)Cout)[o] = bvv;
                    if (col >= 2*DM) {   // V columns -> also write V^T [b*NH+h][d][t]
                        int hh = (col - 2*DM) >> 6, dd = (col - 2*DM) & 63;
                        int bb = row >> 10, tt = row & 1023;
                        vt[(((size_t)bb*NH + hh)*64 + dd)*TT + tt] = bvv;
                    }
                } else if (MODE == 2) {
                    ((float*)Cout)[o] = v + res[o];
                } else {
                    ((__hip_bfloat16*)Cout)[o] = __float2bfloat16(mgelu_f(v));
                }
            }
        }
    }
}

// ---------------- MFMA flash attention ----------------
// grid: BB*NH*(TT/64) blocks, 256 thr (4 waves). Wave w owns q rows q0+w*16..+15.
// S^T = K @ Q^T via mfma(K-frag, Q-frag): lane(kq,lr) reg jj = S[kv=t*16+kq*4+jj][q=w*16+lr].
// K tile [64 kv][64 d] and V^T tile [64 d][64 kv] staged via global_load_lds with
// pre-swizzled source (linear LDS dest; read addr ^= ((row&7)<<4)) -- rule #21 pattern.
__global__ __launch_bounds__(256) void mfma_attn_kernel(const __hip_bfloat16* __restrict__ qkv,
                                                        const __hip_bfloat16* __restrict__ vt,
                                                        __hip_bfloat16* __restrict__ y) {
    __shared__ __align__(16) char K_lds[8192];        // [64 kv][128B d], byte ^ ((kv&7)<<4)
    __shared__ __align__(16) char VT_lds[8192];       // [64 d][128B kv], byte ^ ((d&7)<<4)
    __shared__ __align__(16) char P_lds[4][2048];     // per-wave [16 q][128B kv], ^ ((q&7)<<4)

    int qt = blockIdx.x & 15;
    int h  = (blockIdx.x >> 4) % NH;
    int b  = blockIdx.x / (16*NH);
    int tid = threadIdx.x;
    int lane = tid & 63, w = tid >> 6;
    int lr = lane & 15, kq = lane >> 4;
    int q0 = qt * 64;

    // staging geometry: chunk lx = w + t*4 covers rows lx*8..lx*8+7
    int sr = lane >> 3;                   // 0..7 row-within-chunk
    int scb = (lane & 7) * 16;            // colByte 0..112

    // Q fragments (row q0+w*16+lr, head-dim 64 -> 2 k-steps)
    int qrow = q0 + w*16 + lr;
    const __hip_bfloat16* qp = qkv + (size_t)(b*TT + qrow)*3*DM + h*64;
    bf16x8 qfrag[2];
    qfrag[0] = *(const bf16x8*)(qp + kq*8);
    qfrag[1] = *(const bf16x8*)(qp + 32 + kq*8);

    f32x4 oacc[4] = {};
    float m_run = -INFINITY, l_run = 0.f;
    const float scale = 0.125f;

    const char* kbase  = (const char*)qkv + ((size_t)b*TT*3*DM + DM + h*64)*2;
    const char* vtbase = (const char*)vt + ((size_t)(b*NH + h)*64)*TT*2;

    for (int kt = 0; kt <= qt; ++kt) {
        int kv0 = kt*64;
        // ---- stage K + V^T (pre-swizzled source, linear LDS dest)
        #pragma unroll
        for (int t = 0; t < 2; t++) {
            int lx = w + t*4;                     // 0..7
            int r = lx*8 + sr;                    // tile row
            int cbs = scb ^ ((r & 7) << 4);       // inverse-swizzled source colByte
            const char* gk = kbase + (size_t)(kv0 + r)*3*DM*2 + cbs;
            __builtin_amdgcn_global_load_lds(
                (const __attribute__((address_space(1))) void*)gk,
                (__attribute__((address_space(3))) void*)(K_lds + lx*1024), 16, 0, 0);
            const char* gv = vtbase + (size_t)r*TT*2 + kv0*2 + cbs;
            __builtin_amdgcn_global_load_lds(
                (const __attribute__((address_space(1))) void*)gv,
                (__attribute__((address_space(3))) void*)(VT_lds + lx*1024), 16, 0, 0);
        }
        __syncthreads();

        // ---- S^T tiles
        f32x4 st[4] = {};
        #pragma unroll
        for (int t = 0; t < 4; ++t) {
            #pragma unroll
            for (int ks = 0; ks < 2; ++ks) {
                int row = t*16 + lr;
                bf16x8 kf = *(const bf16x8*)(K_lds + row*128 + ((ks*64 + kq*16) ^ ((lr&7)<<4)));
                st[t] = __builtin_amdgcn_mfma_f32_16x16x32_bf16(kf, qfrag[ks], st[t], 0,0,0);
            }
        }

        // ---- online softmax (per q-row = lr; reduce across kq groups)
        float sv[4][4];
        bool diag = (kt == qt);
        float pmax = -INFINITY;
        #pragma unroll
        for (int t = 0; t < 4; ++t)
            #pragma unroll
            for (int jj = 0; jj < 4; ++jj) {
                float s = st[t][jj] * scale;
                if (diag && (t*16 + kq*4 + jj > w*16 + lr)) s = -INFINITY;
                sv[t][jj] = s;
                pmax = fmaxf(pmax, s);
            }
        pmax = fmaxf(pmax, __shfl_xor(pmax, 16));
        pmax = fmaxf(pmax, __shfl_xor(pmax, 32));
        float m_new = fmaxf(m_run, pmax);
        float corr = __expf(m_run - m_new);
        float rsum = 0.f;
        #pragma unroll
        for (int t = 0; t < 4; ++t)
            #pragma unroll
            for (int jj = 0; jj < 4; ++jj) {
                float p = __expf(sv[t][jj] - m_new);
                sv[t][jj] = p;
                rsum += p;
            }
        rsum += __shfl_xor(rsum, 16);
        rsum += __shfl_xor(rsum, 32);
        l_run = l_run * corr + rsum;
        m_run = m_new;

        // corr lives on lanes keyed by q=lr; oacc rows are q=kq*4+jj -> shfl redistribute
        #pragma unroll
        for (int jj = 0; jj < 4; ++jj) {
            float c = __shfl(corr, kq*20 + jj);   // lane kq*16 + (kq*4+jj)
            #pragma unroll
            for (int nt = 0; nt < 4; ++nt) oacc[nt][jj] *= c;
        }

        // ---- P -> LDS (bf16, swizzled) for A-fragment re-layout
        #pragma unroll
        for (int t = 0; t < 4; ++t) {
            unsigned pk0 = (unsigned)f2bf(sv[t][0]) | ((unsigned)f2bf(sv[t][1]) << 16);
            unsigned pk1 = (unsigned)f2bf(sv[t][2]) | ((unsigned)f2bf(sv[t][3]) << 16);
            unsigned off = ((unsigned)(lr*128 + t*32 + kq*8)) ^ (((unsigned)lr&7u)<<4);
            *(uint2*)(P_lds[w] + off) = make_uint2(pk0, pk1);
        }

        // ---- PV: O[16 q][64 d] += P @ V  (B-frag from V^T: plain swizzled reads)
        #pragma unroll
        for (int ks = 0; ks < 2; ++ks) {
            bf16x8 pa = *(const bf16x8*)(P_lds[w] +
                ((unsigned)(lr*128 + ((ks*64 + kq*16) ^ ((lr&7)<<4)))));
            #pragma unroll
            for (int nt = 0; nt < 4; ++nt) {
                int row = nt*16 + lr;   // d
                bf16x8 vf = *(const bf16x8*)(VT_lds + row*128 + ((ks*64 + kq*16) ^ ((lr&7)<<4)));
                oacc[nt] = __builtin_amdgcn_mfma_f32_16x16x32_bf16(pa, vf, oacc[nt], 0,0,0);
            }
        }
        __syncthreads();
    }

    // ---- epilogue: divide by l (per q-row) and store
    #pragma unroll
    for (int jj = 0; jj < 4; ++jj) {
        float li = __shfl(l_run, kq*20 + jj);
        int qg = q0 + w*16 + kq*4 + jj;
        #pragma unroll
        for (int nt = 0; nt < 4; ++nt)
            y[(size_t)(b*TT + qg)*DM + h*64 + nt*16 + lr] =
                __float2bfloat16(oacc[nt][jj] / li);
    }
}

// ---------------- loss ----------------
__global__ void zero_acc_kernel(float* p) { p[threadIdx.x] = 0.f; }

__global__ __launch_bounds__(256) void loss_kernel(const float* __restrict__ logits,
                                                   const int* __restrict__ targets,
                                                   float* __restrict__ acc) {
    int row = blockIdx.x;
    int tid = threadIdx.x;
    __shared__ float red[256];
    const float* lr = logits + (size_t)row * VOC;
    float mx = -INFINITY;
    for (int c = tid; c < VOC; c += 256) mx = fmaxf(mx, lr[c]);
    red[tid] = mx; __syncthreads();
    for (int off = 128; off > 0; off >>= 1) {
        if (tid < off) red[tid] = fmaxf(red[tid], red[tid+off]);
        __syncthreads();
    }
    mx = red[0]; __syncthreads();
    float se = 0.f;
    for (int c = tid; c < VOC; c += 256) se += expf(lr[c] - mx);
    red[tid] = se; __syncthreads();
    for (int off = 128; off > 0; off >>= 1) {
        if (tid < off) red[tid] += red[tid+off];
        __syncthreads();
    }
    if (tid == 0) {
        int tgt = targets[row];
        if (tgt >= 0) {
            float lse = logf(red[0]) + mx;
            atomicAdd(&acc[0], lse - lr[tgt]);
            atomicAdd(&acc[1], 1.f);
        }
    }
}

__global__ void loss_final_kernel(const float* acc, float* out) {
    out[0] = acc[0] / acc[1];
}

// ---------------- launch ----------------
extern "C" void kernel_launch(void* const* d_in, const int* in_sizes, int n_in,
                              void* d_out, int out_size, void* d_ws, size_t ws_size,
                              hipStream_t stream) {
    const int*   idx     = (const int*)  d_in[0];
    const int*   targets = (const int*)  d_in[1];
    const float* wte     = (const float*)d_in[2];
    const float* wpe     = (const float*)d_in[3];
    const float* ln1_g   = (const float*)d_in[4];
    const float* ln1_b   = (const float*)d_in[5];
    const float* qkv_w   = (const float*)d_in[6];
    const float* qkv_b   = (const float*)d_in[7];
    const float* po_w    = (const float*)d_in[8];
    const float* po_b    = (const float*)d_in[9];
    const float* ln2_g   = (const float*)d_in[10];
    const float* ln2_b   = (const float*)d_in[11];
    const float* fc_w    = (const float*)d_in[12];
    const float* fc_b    = (const float*)d_in[13];
    const float* pr_w    = (const float*)d_in[14];
    const float* pr_b    = (const float*)d_in[15];
    const float* lnf_g   = (const float*)d_in[16];
    const float* lnf_b   = (const float*)d_in[17];
    const float* lm_w    = (const float*)d_in[18];

    float* logits = (float*)d_out;                 // [MR][VOC], loss appended

    char* p = (char*)d_ws;
    float* x = (float*)p;                 p += (size_t)MR*DM*4;
    __hip_bfloat16* h    = (__hip_bfloat16*)p; p += (size_t)MR*DM*2;
    __hip_bfloat16* qkvb = (__hip_bfloat16*)p; p += (size_t)MR*3*DM*2;
    __hip_bfloat16* yb   = (__hip_bfloat16*)p; p += (size_t)MR*DM*2;
    __hip_bfloat16* fb   = (__hip_bfloat16*)p; p += (size_t)MR*FF*2;
    __hip_bfloat16* vtb  = (__hip_bfloat16*)p; p += (size_t)BB*NH*64*TT*2;
    __hip_bfloat16* lm_wt  = (__hip_bfloat16*)p; p += (size_t)VOC*DM*2;
    __hip_bfloat16* qkv_wt = (__hip_bfloat16*)p; p += (size_t)3*DM*DM*2;
    __hip_bfloat16* po_wt  = (__hip_bfloat16*)p; p += (size_t)DM*DM*2;
    __hip_bfloat16* fc_wt  = (__hip_bfloat16*)p; p += (size_t)FF*DM*2;
    __hip_bfloat16* pr_wt  = (__hip_bfloat16*)p; p += (size_t)DM*FF*2;
    float* lacc = (float*)p;

    dim3 tpb(32, 8);

    embed_kernel<<<MR, 256, 0, stream>>>(idx, wte, wpe, x);

    transpose_cvt_kernel<<<dim3((VOC+31)/32, (DM+31)/32), tpb, 0, stream>>>(lm_w, lm_wt, DM, VOC);

    for (int l = 0; l < NL; l++) {
        transpose_cvt_kernel<<<dim3((3*DM+31)/32, (DM+31)/32), tpb, 0, stream>>>(
            qkv_w + (size_t)l*DM*3*DM, qkv_wt, DM, 3*DM);
        transpose_cvt_kernel<<<dim3((DM+31)/32, (DM+31)/32), tpb, 0, stream>>>(
            po_w + (size_t)l*DM*DM, po_wt, DM, DM);
        transpose_cvt_kernel<<<dim3((FF+31)/32, (DM+31)/32), tpb, 0, stream>>>(
            fc_w + (size_t)l*DM*FF, fc_wt, DM, FF);
        transpose_cvt_kernel<<<dim3((DM+31)/32, (FF+31)/32), tpb, 0, stream>>>(
            pr_w + (size_t)l*FF*DM, pr_wt, FF, DM);

        ln_kernel<<<MR, 64, 0, stream>>>(x, ln1_g + l*DM, ln1_b + l*DM, h);
        mfma_gemm_kernel<1><<<dim3(3*DM/128, MR/128), 256, 0, stream>>>(
            h, qkv_wt, qkv_b + (size_t)l*3*DM, nullptr, qkvb, vtb, MR, 3*DM, DM);
        mfma_attn_kernel<<<BB*NH*(TT/64), 256, 0, stream>>>(qkvb, vtb, yb);
        mfma_gemm_kernel<2><<<dim3(DM/128, MR/128), 256, 0, stream>>>(
            yb, po_wt, po_b + (size_t)l*DM, x, x, nullptr, MR, DM, DM);
        ln_kernel<<<MR, 64, 0, stream>>>(x, ln2_g + l*DM, ln2_b + l*DM, h);
        mfma_gemm_kernel<3><<<dim3(FF/128, MR/128), 256, 0, stream>>>(
            h, fc_wt, fc_b + (size_t)l*FF, nullptr, fb, nullptr, MR, FF, DM);
        mfma_gemm_kernel<2><<<dim3(DM/128, MR/128), 256, 0, stream>>>(
            fb, pr_wt, pr_b + (size_t)l*DM, x, x, nullptr, MR, DM, FF);
    }

    ln_kernel<<<MR, 64, 0, stream>>>(x, lnf_g, lnf_b, h);
    mfma_gemm_kernel<0><<<dim3((VOC+127)/128, MR/128), 256, 0, stream>>>(
        h, lm_wt, nullptr, nullptr, logits, nullptr, MR, VOC, DM);

    zero_acc_kernel<<<1, 2, 0, stream>>>(lacc);
    loss_kernel<<<MR, 256, 0, stream>>>(logits, targets, lacc);
    loss_final_kernel<<<1, 1, 0, stream>>>(lacc, logits + (size_t)MR*VOC);
}

// Round 5
// 3435.777 us; speedup vs baseline: 7.0244x; 1.1559x over previous
//
#include <hip/hip_runtime.h>
#include <hip/hip_bf16.h>
#include <math.h>

#define VOC 50257
#define NL 12
#define NH 12
#define DM 768
#define FF 3072
#define BB 2
#define TT 1024
#define MR (BB*TT)   // 2048 rows

typedef __attribute__((ext_vector_type(8))) short bf16x8;
typedef __attribute__((ext_vector_type(4))) float f32x4;

__device__ __forceinline__ float mgelu_f(float x) {
    return 0.5f*x*(1.f + tanhf(0.7978845608028654f*(x + 0.047715f*x*x*x)));
}

__device__ __forceinline__ unsigned short f2bf(float f) {
    __hip_bfloat16 h = __float2bfloat16(f);
    return *reinterpret_cast<unsigned short*>(&h);
}

// XCD-chunked bijective remap (m204): blockIdx round-robins across 8 XCDs;
// give each XCD a contiguous work range so L2-shared panels stay resident.
__device__ __forceinline__ int xcd_work(int bid, int total) {
    int xcd = bid & 7;
    int seq = bid >> 3;
    int q = total >> 3, r = total & 7;
    int base = (xcd < r) ? xcd*(q+1) : r + xcd*q;
    return base + seq;
}

// ---------------- embedding ----------------
__global__ void embed_kernel(const int* __restrict__ idx, const float* __restrict__ wte,
                             const float* __restrict__ wpe, float* __restrict__ x) {
    int row = blockIdx.x;
    int t = row % TT;
    int tok = idx[row];
    for (int d = threadIdx.x; d < DM; d += blockDim.x)
        x[(size_t)row*DM + d] = wte[(size_t)tok*DM + d] + wpe[(size_t)t*DM + d];
}

// ---------------- layernorm: 4 rows/block (one wave each) ----------------
__global__ __launch_bounds__(256) void ln_kernel(const float* __restrict__ x,
                          const float* __restrict__ g,
                          const float* __restrict__ b, __hip_bfloat16* __restrict__ out) {
    int row = blockIdx.x*4 + (threadIdx.x >> 6);
    int lane = threadIdx.x & 63;
    const float* xr = x + (size_t)row*DM;
    float vals[DM/64];
    float s = 0.f;
    #pragma unroll
    for (int i = 0; i < DM/64; i++) { vals[i] = xr[lane + i*64]; s += vals[i]; }
    #pragma unroll
    for (int off = 32; off > 0; off >>= 1) s += __shfl_xor(s, off);
    float mean = s * (1.0f/DM);
    float vs = 0.f;
    #pragma unroll
    for (int i = 0; i < DM/64; i++) { float d = vals[i]-mean; vs += d*d; }
    #pragma unroll
    for (int off = 32; off > 0; off >>= 1) vs += __shfl_xor(vs, off);
    float rstd = rsqrtf(vs * (1.0f/DM) + 1e-5f);
    #pragma unroll
    for (int i = 0; i < DM/64; i++) {
        int d = lane + i*64;
        out[(size_t)row*DM + d] = __float2bfloat16((vals[i]-mean)*rstd*g[d] + b[d]);
    }
}

// ---------------- fused 4x transpose+cvt: in [R][C] -> out [C][R] ----------------
struct TJob { const float* in; __hip_bfloat16* out; int R, C, cx, tile0; };

__device__ __forceinline__ void trans_one(const TJob& j, int t) {
    __shared__ float tile[32][33];
    int bx = t % j.cx, by = t / j.cx;
    int c0 = bx*32, r0 = by*32;
    int tx = threadIdx.x, ty = threadIdx.y;   // 32 x 8
    #pragma unroll
    for (int i = ty; i < 32; i += 8) {
        int r = r0 + i, c = c0 + tx;
        tile[i][tx] = (r < j.R && c < j.C) ? j.in[(size_t)r*j.C + c] : 0.f;
    }
    __syncthreads();
    #pragma unroll
    for (int i = ty; i < 32; i += 8) {
        int c = c0 + i, r = r0 + tx;
        if (c < j.C && r < j.R) j.out[(size_t)c*j.R + r] = __float2bfloat16(tile[tx][i]);
    }
}

__global__ void trans4_kernel(TJob j0, TJob j1, TJob j2, TJob j3) {
    int t = blockIdx.x;
    if (t >= j3.tile0)      trans_one(j3, t - j3.tile0);
    else if (t >= j2.tile0) trans_one(j2, t - j2.tile0);
    else if (t >= j1.tile0) trans_one(j1, t - j1.tile0);
    else                    trans_one(j0, t);
}

__global__ void trans1_kernel(TJob j0) { trans_one(j0, blockIdx.x); }

// ---------------- MFMA bf16 GEMM: C = epi(A @ Wt^T + bias) ----------------
// A [M][K] bf16, Wt [N][K] bf16. Tile BMx128, BK=32, 256 thr (4 waves).
// HALFM=0: BM=128, waves 2x2 (64x64 each). HALFM=1: BM=64, waves 1x4 (64x32 each).
// MODE: 0 = f32 out; 1 = bf16 out +bias (+V^T side-write); 2 = f32 +bias+res; 3 = bf16 gelu+bias
template<int MODE, int HALFM>
__global__ __launch_bounds__(256) void mfma_gemm_kernel(
        const __hip_bfloat16* __restrict__ A,
        const __hip_bfloat16* __restrict__ Wt,
        const float* __restrict__ bias,
        const float* __restrict__ res,
        void* __restrict__ Cout,
        __hip_bfloat16* __restrict__ vt,
        int M, int N, int K) {
    constexpr int BM = HALFM ? 64 : 128;
    constexpr int NF = HALFM ? 2 : 4;
    __shared__ __align__(16) char As[BM*64];    // [4 kq][BM][16B]
    __shared__ __align__(16) char Bs[8192];     // [4 kq][128][16B]
    int tid = threadIdx.x;
    int lane = tid & 63, wid = tid >> 6;
    int kq = lane >> 4, lr = lane & 15;

    int nby = M / BM;
    int work = xcd_work(blockIdx.x, gridDim.x);
    int by = work % nby;          // M-tile inner: consecutive works share W panel
    int bx = work / nby;
    int m0 = by * BM, n0 = bx * 128;

    int wm = HALFM ? 0 : (wid >> 1);
    int wn = HALFM ? wid : (wid & 1);
    int colbase = HALFM ? wn*32 : wn*64;

    f32x4 acc[4][NF] = {};

    for (int k0 = 0; k0 < K; k0 += 32) {
        if constexpr (HALFM) {
            // A: 4 chunks, one per wave
            const __hip_bfloat16* ga = A + (size_t)(m0 + lane)*K + k0 + wid*8;
            __builtin_amdgcn_global_load_lds(
                (const __attribute__((address_space(1))) void*)ga,
                (__attribute__((address_space(3))) void*)(As + wid*1024), 16, 0, 0);
            // B: 8 chunks, two per wave
            #pragma unroll
            for (int t = 0; t < 2; t++) {
                int lx = wid + t*4;
                int r  = (lx & 1)*64 + lane;
                int kk = (lx >> 1)*8;
                int nr = n0 + r; if (nr > N-1) nr = N-1;
                const __hip_bfloat16* gb = Wt + (size_t)nr*K + k0 + kk;
                __builtin_amdgcn_global_load_lds(
                    (const __attribute__((address_space(1))) void*)gb,
                    (__attribute__((address_space(3))) void*)(Bs + lx*1024), 16, 0, 0);
            }
        } else {
            #pragma unroll
            for (int t = 0; t < 2; t++) {
                int lx = wid + t*4;
                int r  = (lx & 1)*64 + lane;
                int kk = (lx >> 1)*8;
                const __hip_bfloat16* ga = A + (size_t)(m0 + r)*K + k0 + kk;
                __builtin_amdgcn_global_load_lds(
                    (const __attribute__((address_space(1))) void*)ga,
                    (__attribute__((address_space(3))) void*)(As + lx*1024), 16, 0, 0);
                int nr = n0 + r; if (nr > N-1) nr = N-1;
                const __hip_bfloat16* gb = Wt + (size_t)nr*K + k0 + kk;
                __builtin_amdgcn_global_load_lds(
                    (const __attribute__((address_space(1))) void*)gb,
                    (__attribute__((address_space(3))) void*)(Bs + lx*1024), 16, 0, 0);
            }
        }
        __syncthreads();

        bf16x8 afrag[4], bfrag[NF];
        #pragma unroll
        for (int m = 0; m < 4; m++)
            afrag[m] = *(const bf16x8*)(As + kq*(BM*16) + (wm*64 + m*16 + lr)*16);
        #pragma unroll
        for (int n = 0; n < NF; n++)
            bfrag[n] = *(const bf16x8*)(Bs + kq*2048 + (colbase + n*16 + lr)*16);
        #pragma unroll
        for (int m = 0; m < 4; m++)
            #pragma unroll
            for (int n = 0; n < NF; n++)
                acc[m][n] = __builtin_amdgcn_mfma_f32_16x16x32_bf16(afrag[m], bfrag[n], acc[m][n], 0, 0, 0);
        __syncthreads();
    }

    #pragma unroll
    for (int m = 0; m < 4; m++) {
        #pragma unroll
        for (int n = 0; n < NF; n++) {
            int col = n0 + colbase + n*16 + lr;
            if (col >= N) continue;
            float bv = (MODE == 0) ? 0.f : bias[col];
            #pragma unroll
            for (int j = 0; j < 4; j++) {
                int row = m0 + wm*64 + m*16 + kq*4 + j;
                float v = acc[m][n][j] + bv;
                size_t o = (size_t)row*N + col;
                if (MODE == 0) {
                    ((float*)Cout)[o] = v;
                } else if (MODE == 1) {
                    __hip_bfloat16 bvv = __float2bfloat16(v);
                    ((__hip_bfloat16*)Cout)[o] = bvv;
                    if (col >= 2*DM) {   // V columns -> also write V^T [b*NH+h][d][t]
                        int hh = (col - 2*DM) >> 6, dd = (col - 2*DM) & 63;
                        int bb = row >> 10, tt = row & 1023;
                        vt[(((size_t)bb*NH + hh)*64 + dd)*TT + tt] = bvv;
                    }
                } else if (MODE == 2) {
                    ((float*)Cout)[o] = v + res[o];
                } else {
                    ((__hip_bfloat16*)Cout)[o] = __float2bfloat16(mgelu_f(v));
                }
            }
        }
    }
}

// ---------------- MFMA flash attention ----------------
// Chunked XCD remap (K/V of one (b,h) stays in one XCD's L2) + LPT (big qt first).
__global__ __launch_bounds__(256) void mfma_attn_kernel(const __hip_bfloat16* __restrict__ qkv,
                                                        const __hip_bfloat16* __restrict__ vt,
                                                        __hip_bfloat16* __restrict__ y) {
    __shared__ __align__(16) char K_lds[8192];        // [64 kv][128B d], byte ^ ((kv&7)<<4)
    __shared__ __align__(16) char VT_lds[8192];       // [64 d][128B kv], byte ^ ((d&7)<<4)
    __shared__ __align__(16) char P_lds[4][2048];     // per-wave [16 q][128B kv], ^ ((q&7)<<4)

    int work = xcd_work(blockIdx.x, BB*NH*16);
    int qt = 15 - (work & 15);            // LPT: heaviest q-tiles first
    int bh = work >> 4;
    int h  = bh % NH;
    int b  = bh / NH;
    int tid = threadIdx.x;
    int lane = tid & 63, w = tid >> 6;
    int lr = lane & 15, kq = lane >> 4;
    int q0 = qt * 64;

    int sr = lane >> 3;                   // staging row-within-chunk
    int scb = (lane & 7) * 16;            // staging colByte

    int qrow = q0 + w*16 + lr;
    const __hip_bfloat16* qp = qkv + (size_t)(b*TT + qrow)*3*DM + h*64;
    bf16x8 qfrag[2];
    qfrag[0] = *(const bf16x8*)(qp + kq*8);
    qfrag[1] = *(const bf16x8*)(qp + 32 + kq*8);

    f32x4 oacc[4] = {};
    float m_run = -INFINITY, l_run = 0.f;
    const float scale = 0.125f;

    const char* kbase  = (const char*)qkv + ((size_t)b*TT*3*DM + DM + h*64)*2;
    const char* vtbase = (const char*)vt + ((size_t)(b*NH + h)*64)*TT*2;

    for (int kt = 0; kt <= qt; ++kt) {
        int kv0 = kt*64;
        #pragma unroll
        for (int t = 0; t < 2; t++) {
            int lx = w + t*4;
            int r = lx*8 + sr;
            int cbs = scb ^ ((r & 7) << 4);
            const char* gk = kbase + (size_t)(kv0 + r)*3*DM*2 + cbs;
            __builtin_amdgcn_global_load_lds(
                (const __attribute__((address_space(1))) void*)gk,
                (__attribute__((address_space(3))) void*)(K_lds + lx*1024), 16, 0, 0);
            const char* gv = vtbase + (size_t)r*TT*2 + kv0*2 + cbs;
            __builtin_amdgcn_global_load_lds(
                (const __attribute__((address_space(1))) void*)gv,
                (__attribute__((address_space(3))) void*)(VT_lds + lx*1024), 16, 0, 0);
        }
        __syncthreads();

        f32x4 st[4] = {};
        #pragma unroll
        for (int t = 0; t < 4; ++t) {
            #pragma unroll
            for (int ks = 0; ks < 2; ++ks) {
                int row = t*16 + lr;
                bf16x8 kf = *(const bf16x8*)(K_lds + row*128 + ((ks*64 + kq*16) ^ ((lr&7)<<4)));
                st[t] = __builtin_amdgcn_mfma_f32_16x16x32_bf16(kf, qfrag[ks], st[t], 0,0,0);
            }
        }

        float sv[4][4];
        bool diag = (kt == qt);
        float pmax = -INFINITY;
        #pragma unroll
        for (int t = 0; t < 4; ++t)
            #pragma unroll
            for (int jj = 0; jj < 4; ++jj) {
                float s = st[t][jj] * scale;
                if (diag && (t*16 + kq*4 + jj > w*16 + lr)) s = -INFINITY;
                sv[t][jj] = s;
                pmax = fmaxf(pmax, s);
            }
        pmax = fmaxf(pmax, __shfl_xor(pmax, 16));
        pmax = fmaxf(pmax, __shfl_xor(pmax, 32));
        float m_new = fmaxf(m_run, pmax);
        float corr = __expf(m_run - m_new);
        float rsum = 0.f;
        #pragma unroll
        for (int t = 0; t < 4; ++t)
            #pragma unroll
            for (int jj = 0; jj < 4; ++jj) {
                float p = __expf(sv[t][jj] - m_new);
                sv[t][jj] = p;
                rsum += p;
            }
        rsum += __shfl_xor(rsum, 16);
        rsum += __shfl_xor(rsum, 32);
        l_run = l_run * corr + rsum;
        m_run = m_new;

        #pragma unroll
        for (int jj = 0; jj < 4; ++jj) {
            float c = __shfl(corr, kq*20 + jj);
            #pragma unroll
            for (int nt = 0; nt < 4; ++nt) oacc[nt][jj] *= c;
        }

        #pragma unroll
        for (int t = 0; t < 4; ++t) {
            unsigned pk0 = (unsigned)f2bf(sv[t][0]) | ((unsigned)f2bf(sv[t][1]) << 16);
            unsigned pk1 = (unsigned)f2bf(sv[t][2]) | ((unsigned)f2bf(sv[t][3]) << 16);
            unsigned off = ((unsigned)(lr*128 + t*32 + kq*8)) ^ (((unsigned)lr&7u)<<4);
            *(uint2*)(P_lds[w] + off) = make_uint2(pk0, pk1);
        }

        #pragma unroll
        for (int ks = 0; ks < 2; ++ks) {
            bf16x8 pa = *(const bf16x8*)(P_lds[w] +
                ((unsigned)(lr*128 + ((ks*64 + kq*16) ^ ((lr&7)<<4)))));
            #pragma unroll
            for (int nt = 0; nt < 4; ++nt) {
                int row = nt*16 + lr;
                bf16x8 vf = *(const bf16x8*)(VT_lds + row*128 + ((ks*64 + kq*16) ^ ((lr&7)<<4)));
                oacc[nt] = __builtin_amdgcn_mfma_f32_16x16x32_bf16(pa, vf, oacc[nt], 0,0,0);
            }
        }
        __syncthreads();
    }

    #pragma unroll
    for (int jj = 0; jj < 4; ++jj) {
        float li = __shfl(l_run, kq*20 + jj);
        int qg = q0 + w*16 + kq*4 + jj;
        #pragma unroll
        for (int nt = 0; nt < 4; ++nt)
            y[(size_t)(b*TT + qg)*DM + h*64 + nt*16 + lr] =
                __float2bfloat16(oacc[nt][jj] / li);
    }
}

// ---------------- loss ----------------
__global__ void zero_acc_kernel(float* p) { p[threadIdx.x] = 0.f; }

__global__ __launch_bounds__(256) void loss_kernel(const float* __restrict__ logits,
                                                   const int* __restrict__ targets,
                                                   float* __restrict__ acc) {
    int row = blockIdx.x;
    int tid = threadIdx.x;
    __shared__ float red[256];
    const float* lr = logits + (size_t)row * VOC;
    float mx = -INFINITY;
    for (int c = tid; c < VOC; c += 256) mx = fmaxf(mx, lr[c]);
    red[tid] = mx; __syncthreads();
    for (int off = 128; off > 0; off >>= 1) {
        if (tid < off) red[tid] = fmaxf(red[tid], red[tid+off]);
        __syncthreads();
    }
    mx = red[0]; __syncthreads();
    float se = 0.f;
    for (int c = tid; c < VOC; c += 256) se += expf(lr[c] - mx);
    red[tid] = se; __syncthreads();
    for (int off = 128; off > 0; off >>= 1) {
        if (tid < off) red[tid] += red[tid+off];
        __syncthreads();
    }
    if (tid == 0) {
        int tgt = targets[row];
        if (tgt >= 0) {
            float lse = logf(red[0]) + mx;
            atomicAdd(&acc[0], lse - lr[tgt]);
            atomicAdd(&acc[1], 1.f);
        }
    }
}

__global__ void loss_final_kernel(const float* acc, float* out) {
    out[0] = acc[0] / acc[1];
}

// ---------------- launch ----------------
static inline TJob mkjob(const float* in, __hip_bfloat16* out, int R, int C, int tile0) {
    TJob j; j.in = in; j.out = out; j.R = R; j.C = C;
    j.cx = (C + 31)/32; j.tile0 = tile0;
    return j;
}

extern "C" void kernel_launch(void* const* d_in, const int* in_sizes, int n_in,
                              void* d_out, int out_size, void* d_ws, size_t ws_size,
                              hipStream_t stream) {
    const int*   idx     = (const int*)  d_in[0];
    const int*   targets = (const int*)  d_in[1];
    const float* wte     = (const float*)d_in[2];
    const float* wpe     = (const float*)d_in[3];
    const float* ln1_g   = (const float*)d_in[4];
    const float* ln1_b   = (const float*)d_in[5];
    const float* qkv_w   = (const float*)d_in[6];
    const float* qkv_b   = (const float*)d_in[7];
    const float* po_w    = (const float*)d_in[8];
    const float* po_b    = (const float*)d_in[9];
    const float* ln2_g   = (const float*)d_in[10];
    const float* ln2_b   = (const float*)d_in[11];
    const float* fc_w    = (const float*)d_in[12];
    const float* fc_b    = (const float*)d_in[13];
    const float* pr_w    = (const float*)d_in[14];
    const float* pr_b    = (const float*)d_in[15];
    const float* lnf_g   = (const float*)d_in[16];
    const float* lnf_b   = (const float*)d_in[17];
    const float* lm_w    = (const float*)d_in[18];

    float* logits = (float*)d_out;                 // [MR][VOC], loss appended

    char* p = (char*)d_ws;
    float* x = (float*)p;                 p += (size_t)MR*DM*4;
    __hip_bfloat16* h    = (__hip_bfloat16*)p; p += (size_t)MR*DM*2;
    __hip_bfloat16* qkvb = (__hip_bfloat16*)p; p += (size_t)MR*3*DM*2;
    __hip_bfloat16* yb   = (__hip_bfloat16*)p; p += (size_t)MR*DM*2;
    __hip_bfloat16* fb   = (__hip_bfloat16*)p; p += (size_t)MR*FF*2;
    __hip_bfloat16* vtb  = (__hip_bfloat16*)p; p += (size_t)BB*NH*64*TT*2;
    __hip_bfloat16* lm_wt  = (__hip_bfloat16*)p; p += (size_t)VOC*DM*2;
    __hip_bfloat16* qkv_wt = (__hip_bfloat16*)p; p += (size_t)3*DM*DM*2;
    __hip_bfloat16* po_wt  = (__hip_bfloat16*)p; p += (size_t)DM*DM*2;
    __hip_bfloat16* fc_wt  = (__hip_bfloat16*)p; p += (size_t)FF*DM*2;
    __hip_bfloat16* pr_wt  = (__hip_bfloat16*)p; p += (size_t)DM*FF*2;
    float* lacc = (float*)p;

    dim3 tpb(32, 8);

    embed_kernel<<<MR, 256, 0, stream>>>(idx, wte, wpe, x);

    // LM-head weight transpose (once): tiles = ceil(50257/32)*24
    {
        TJob j = mkjob(lm_w, lm_wt, DM, VOC, 0);
        int tiles = j.cx * ((DM+31)/32);
        trans1_kernel<<<tiles, tpb, 0, stream>>>(j);
    }

    for (int l = 0; l < NL; l++) {
        // fused per-layer weight transposes (one launch)
        TJob j0 = mkjob(qkv_w + (size_t)l*DM*3*DM, qkv_wt, DM, 3*DM, 0);
        int t1 = j0.cx * 24;
        TJob j1 = mkjob(po_w + (size_t)l*DM*DM, po_wt, DM, DM, t1);
        int t2 = t1 + j1.cx * 24;
        TJob j2 = mkjob(fc_w + (size_t)l*DM*FF, fc_wt, DM, FF, t2);
        int t3 = t2 + j2.cx * 24;
        TJob j3 = mkjob(pr_w + (size_t)l*FF*DM, pr_wt, FF, DM, t3);
        int tot = t3 + j3.cx * 96;
        trans4_kernel<<<tot, tpb, 0, stream>>>(j0, j1, j2, j3);

        ln_kernel<<<MR/4, 256, 0, stream>>>(x, ln1_g + l*DM, ln1_b + l*DM, h);
        mfma_gemm_kernel<1,0><<<(3*DM/128)*(MR/128), 256, 0, stream>>>(
            h, qkv_wt, qkv_b + (size_t)l*3*DM, nullptr, qkvb, vtb, MR, 3*DM, DM);
        mfma_attn_kernel<<<BB*NH*(TT/64), 256, 0, stream>>>(qkvb, vtb, yb);
        mfma_gemm_kernel<2,1><<<(DM/128)*(MR/64), 256, 0, stream>>>(
            yb, po_wt, po_b + (size_t)l*DM, x, x, nullptr, MR, DM, DM);
        ln_kernel<<<MR/4, 256, 0, stream>>>(x, ln2_g + l*DM, ln2_b + l*DM, h);
        mfma_gemm_kernel<3,0><<<(FF/128)*(MR/128), 256, 0, stream>>>(
            h, fc_wt, fc_b + (size_t)l*FF, nullptr, fb, nullptr, MR, FF, DM);
        mfma_gemm_kernel<2,1><<<(DM/128)*(MR/64), 256, 0, stream>>>(
            fb, pr_wt, pr_b + (size_t)l*DM, x, x, nullptr, MR, DM, FF);
    }

    ln_kernel<<<MR/4, 256, 0, stream>>>(x, lnf_g, lnf_b, h);
    mfma_gemm_kernel<0,0><<<((VOC+127)/128)*(MR/128), 256, 0, stream>>>(
        h, lm_wt, nullptr, nullptr, logits, nullptr, MR, VOC, DM);

    zero_acc_kernel<<<1, 2, 0, stream>>>(lacc);
    loss_kernel<<<MR, 256, 0, stream>>>(logits, targets, lacc);
    loss_final_kernel<<<1, 1, 0, stream>>>(lacc, logits + (size_t)MR*VOC);
}

// Round 6
// 3291.055 us; speedup vs baseline: 7.3333x; 1.0440x over previous
//
#include <hip/hip_runtime.h>
#include <hip/hip_bf16.h>
#include <math.h>

#define VOC 50257
#define NL 12
#define NH 12
#define DM 768
#define FF 3072
#define BB 2
#define TT 1024
#define MR (BB*TT)   // 2048 rows

typedef __attribute__((ext_vector_type(8))) short bf16x8;
typedef __attribute__((ext_vector_type(4))) float f32x4;

__device__ __forceinline__ float mgelu_f(float x) {
    return 0.5f*x*(1.f + tanhf(0.7978845608028654f*(x + 0.047715f*x*x*x)));
}

__device__ __forceinline__ unsigned short f2bf(float f) {
    __hip_bfloat16 h = __float2bfloat16(f);
    return *reinterpret_cast<unsigned short*>(&h);
}

#define GLDS(gptr, lptr) __builtin_amdgcn_global_load_lds( \
    (const __attribute__((address_space(1))) void*)(gptr), \
    (__attribute__((address_space(3))) void*)(lptr), 16, 0, 0)

// XCD-chunked bijective remap (m204)
__device__ __forceinline__ int xcd_work(int bid, int total) {
    int xcd = bid & 7;
    int seq = bid >> 3;
    int q = total >> 3, r = total & 7;
    int base = (xcd < r) ? xcd*(q+1) : r + xcd*q;
    return base + seq;
}

// ---------------- embedding ----------------
__global__ void embed_kernel(const int* __restrict__ idx, const float* __restrict__ wte,
                             const float* __restrict__ wpe, float* __restrict__ x) {
    int row = blockIdx.x;
    int t = row % TT;
    int tok = idx[row];
    for (int d = threadIdx.x; d < DM; d += blockDim.x)
        x[(size_t)row*DM + d] = wte[(size_t)tok*DM + d] + wpe[(size_t)t*DM + d];
}

// ---------------- layernorm: 4 rows/block (one wave each) ----------------
__global__ __launch_bounds__(256) void ln_kernel(const float* __restrict__ x,
                          const float* __restrict__ g,
                          const float* __restrict__ b, __hip_bfloat16* __restrict__ out) {
    int row = blockIdx.x*4 + (threadIdx.x >> 6);
    int lane = threadIdx.x & 63;
    const float* xr = x + (size_t)row*DM;
    float vals[DM/64];
    float s = 0.f;
    #pragma unroll
    for (int i = 0; i < DM/64; i++) { vals[i] = xr[lane + i*64]; s += vals[i]; }
    #pragma unroll
    for (int off = 32; off > 0; off >>= 1) s += __shfl_xor(s, off);
    float mean = s * (1.0f/DM);
    float vs = 0.f;
    #pragma unroll
    for (int i = 0; i < DM/64; i++) { float d = vals[i]-mean; vs += d*d; }
    #pragma unroll
    for (int off = 32; off > 0; off >>= 1) vs += __shfl_xor(vs, off);
    float rstd = rsqrtf(vs * (1.0f/DM) + 1e-5f);
    #pragma unroll
    for (int i = 0; i < DM/64; i++) {
        int d = lane + i*64;
        out[(size_t)row*DM + d] = __float2bfloat16((vals[i]-mean)*rstd*g[d] + b[d]);
    }
}

// ---------------- fused 4x transpose+cvt: in [R][C] -> out [C][R] ----------------
struct TJob { const float* in; __hip_bfloat16* out; int R, C, cx, tile0; };

__device__ __forceinline__ void trans_one(const TJob& j, int t) {
    __shared__ float tile[32][33];
    int bx = t % j.cx, by = t / j.cx;
    int c0 = bx*32, r0 = by*32;
    int tx = threadIdx.x, ty = threadIdx.y;   // 32 x 8
    #pragma unroll
    for (int i = ty; i < 32; i += 8) {
        int r = r0 + i, c = c0 + tx;
        tile[i][tx] = (r < j.R && c < j.C) ? j.in[(size_t)r*j.C + c] : 0.f;
    }
    __syncthreads();
    #pragma unroll
    for (int i = ty; i < 32; i += 8) {
        int c = c0 + i, r = r0 + tx;
        if (c < j.C && r < j.R) j.out[(size_t)c*j.R + r] = __float2bfloat16(tile[tx][i]);
    }
}

__global__ void trans4_kernel(TJob j0, TJob j1, TJob j2, TJob j3) {
    int t = blockIdx.x;
    if (t >= j3.tile0)      trans_one(j3, t - j3.tile0);
    else if (t >= j2.tile0) trans_one(j2, t - j2.tile0);
    else if (t >= j1.tile0) trans_one(j1, t - j1.tile0);
    else                    trans_one(j0, t);
}

__global__ void trans1_kernel(TJob j0) { trans_one(j0, blockIdx.x); }

// ---------------- MFMA bf16 GEMM, 2-phase double-buffered ----------------
// A [M][K] bf16, Wt [N][K] bf16. Tile BMx128, BK=32, 256 thr (4 waves).
// HALFM=0: BM=128, waves 2x2. HALFM=1: BM=64, waves 1x4.
// Schedule: prologue STAGE(buf0); loop { STAGE(buf^1,next); compute(cur); sync; }
// -> global->LDS latency hides under the MFMA phase (vmcnt(0) drain moves after compute).
template<int MODE, int HALFM>
__global__ __launch_bounds__(256) void mfma_gemm_kernel(
        const __hip_bfloat16* __restrict__ A,
        const __hip_bfloat16* __restrict__ Wt,
        const float* __restrict__ bias,
        const float* __restrict__ res,
        void* __restrict__ Cout,
        __hip_bfloat16* __restrict__ vt,
        int M, int N, int K) {
    constexpr int BM = HALFM ? 64 : 128;
    constexpr int NF = HALFM ? 2 : 4;
    __shared__ __align__(16) char As[2][BM*64];    // [buf][4 kq][BM][16B]
    __shared__ __align__(16) char Bs[2][8192];     // [buf][4 kq][128][16B]
    int tid = threadIdx.x;
    int lane = tid & 63, wid = tid >> 6;
    int kq = lane >> 4, lr = lane & 15;

    int nby = M / BM;
    int work = xcd_work(blockIdx.x, gridDim.x);
    int by = work % nby;          // M-tile inner: consecutive works share W panel
    int bx = work / nby;
    int m0 = by * BM, n0 = bx * 128;

    int wm = HALFM ? 0 : (wid >> 1);
    int wn = HALFM ? wid : (wid & 1);
    int colbase = HALFM ? wn*32 : wn*64;

    f32x4 acc[4][NF] = {};

    auto STAGE = [&](int buf, int k0) {
        if constexpr (HALFM) {
            GLDS(A + (size_t)(m0 + lane)*K + k0 + wid*8, As[buf] + wid*1024);
            #pragma unroll
            for (int t = 0; t < 2; t++) {
                int lx = wid + t*4;
                int r  = (lx & 1)*64 + lane;
                int kk = (lx >> 1)*8;
                int nr = n0 + r; if (nr > N-1) nr = N-1;
                GLDS(Wt + (size_t)nr*K + k0 + kk, Bs[buf] + lx*1024);
            }
        } else {
            #pragma unroll
            for (int t = 0; t < 2; t++) {
                int lx = wid + t*4;
                int r  = (lx & 1)*64 + lane;
                int kk = (lx >> 1)*8;
                GLDS(A + (size_t)(m0 + r)*K + k0 + kk, As[buf] + lx*1024);
                int nr = n0 + r; if (nr > N-1) nr = N-1;
                GLDS(Wt + (size_t)nr*K + k0 + kk, Bs[buf] + lx*1024);
            }
        }
    };

    int nk = K >> 5;
    STAGE(0, 0);
    __syncthreads();
    for (int ki = 0; ki < nk; ++ki) {
        int cur = ki & 1;
        if (ki + 1 < nk) STAGE(cur ^ 1, (ki+1)*32);

        bf16x8 afrag[4], bfrag[NF];
        #pragma unroll
        for (int m = 0; m < 4; m++)
            afrag[m] = *(const bf16x8*)(As[cur] + kq*(BM*16) + (wm*64 + m*16 + lr)*16);
        #pragma unroll
        for (int n = 0; n < NF; n++)
            bfrag[n] = *(const bf16x8*)(Bs[cur] + kq*2048 + (colbase + n*16 + lr)*16);
        #pragma unroll
        for (int m = 0; m < 4; m++)
            #pragma unroll
            for (int n = 0; n < NF; n++)
                acc[m][n] = __builtin_amdgcn_mfma_f32_16x16x32_bf16(afrag[m], bfrag[n], acc[m][n], 0, 0, 0);
        __syncthreads();   // drains stage loads (vmcnt 0) + read-completion for buffer swap
    }

    #pragma unroll
    for (int m = 0; m < 4; m++) {
        #pragma unroll
        for (int n = 0; n < NF; n++) {
            int col = n0 + colbase + n*16 + lr;
            if (col >= N) continue;
            float bv = (MODE == 0) ? 0.f : bias[col];
            #pragma unroll
            for (int j = 0; j < 4; j++) {
                int row = m0 + wm*64 + m*16 + kq*4 + j;
                float v = acc[m][n][j] + bv;
                size_t o = (size_t)row*N + col;
                if (MODE == 0) {
                    ((float*)Cout)[o] = v;
                } else if (MODE == 1) {
                    __hip_bfloat16 bvv = __float2bfloat16(v);
                    ((__hip_bfloat16*)Cout)[o] = bvv;
                    if (col >= 2*DM) {   // V columns -> also write V^T [b*NH+h][d][t]
                        int hh = (col - 2*DM) >> 6, dd = (col - 2*DM) & 63;
                        int bb = row >> 10, tt = row & 1023;
                        vt[(((size_t)bb*NH + hh)*64 + dd)*TT + tt] = bvv;
                    }
                } else if (MODE == 2) {
                    ((float*)Cout)[o] = v + res[o];
                } else {
                    ((__hip_bfloat16*)Cout)[o] = __float2bfloat16(mgelu_f(v));
                }
            }
        }
    }
}

// ---------------- MFMA flash attention, 2-phase double-buffered K/V staging ----------------
__global__ __launch_bounds__(256) void mfma_attn_kernel(const __hip_bfloat16* __restrict__ qkv,
                                                        const __hip_bfloat16* __restrict__ vt,
                                                        __hip_bfloat16* __restrict__ y) {
    __shared__ __align__(16) char K_lds[2][8192];     // [64 kv][128B d], byte ^ ((kv&7)<<4)
    __shared__ __align__(16) char VT_lds[2][8192];    // [64 d][128B kv], byte ^ ((d&7)<<4)
    __shared__ __align__(16) char P_lds[4][2048];     // per-wave [16 q][128B kv], ^ ((q&7)<<4)

    int work = xcd_work(blockIdx.x, BB*NH*16);
    int qt = 15 - (work & 15);            // LPT: heaviest q-tiles first
    int bh = work >> 4;
    int h  = bh % NH;
    int b  = bh / NH;
    int tid = threadIdx.x;
    int lane = tid & 63, w = tid >> 6;
    int lr = lane & 15, kq = lane >> 4;
    int q0 = qt * 64;

    int sr = lane >> 3;                   // staging row-within-chunk
    int scb = (lane & 7) * 16;            // staging colByte

    int qrow = q0 + w*16 + lr;
    const __hip_bfloat16* qp = qkv + (size_t)(b*TT + qrow)*3*DM + h*64;
    bf16x8 qfrag[2];
    qfrag[0] = *(const bf16x8*)(qp + kq*8);
    qfrag[1] = *(const bf16x8*)(qp + 32 + kq*8);

    f32x4 oacc[4] = {};
    float m_run = -INFINITY, l_run = 0.f;
    const float scale = 0.125f;

    const char* kbase  = (const char*)qkv + ((size_t)b*TT*3*DM + DM + h*64)*2;
    const char* vtbase = (const char*)vt + ((size_t)(b*NH + h)*64)*TT*2;

    auto STAGE = [&](int buf, int kt) {
        int kv0 = kt*64;
        #pragma unroll
        for (int t = 0; t < 2; t++) {
            int lx = w + t*4;
            int r = lx*8 + sr;
            int cbs = scb ^ ((r & 7) << 4);
            GLDS(kbase + (size_t)(kv0 + r)*3*DM*2 + cbs, K_lds[buf] + lx*1024);
            GLDS(vtbase + (size_t)r*TT*2 + kv0*2 + cbs, VT_lds[buf] + lx*1024);
        }
    };

    STAGE(0, 0);
    __syncthreads();
    for (int kt = 0; kt <= qt; ++kt) {
        int cur = kt & 1;
        if (kt < qt) STAGE(cur ^ 1, kt + 1);

        f32x4 st[4] = {};
        #pragma unroll
        for (int t = 0; t < 4; ++t) {
            #pragma unroll
            for (int ks = 0; ks < 2; ++ks) {
                int row = t*16 + lr;
                bf16x8 kf = *(const bf16x8*)(K_lds[cur] + row*128 + ((ks*64 + kq*16) ^ ((lr&7)<<4)));
                st[t] = __builtin_amdgcn_mfma_f32_16x16x32_bf16(kf, qfrag[ks], st[t], 0,0,0);
            }
        }

        float sv[4][4];
        bool diag = (kt == qt);
        float pmax = -INFINITY;
        #pragma unroll
        for (int t = 0; t < 4; ++t)
            #pragma unroll
            for (int jj = 0; jj < 4; ++jj) {
                float s = st[t][jj] * scale;
                if (diag && (t*16 + kq*4 + jj > w*16 + lr)) s = -INFINITY;
                sv[t][jj] = s;
                pmax = fmaxf(pmax, s);
            }
        pmax = fmaxf(pmax, __shfl_xor(pmax, 16));
        pmax = fmaxf(pmax, __shfl_xor(pmax, 32));
        float m_new = fmaxf(m_run, pmax);
        float corr = __expf(m_run - m_new);
        float rsum = 0.f;
        #pragma unroll
        for (int t = 0; t < 4; ++t)
            #pragma unroll
            for (int jj = 0; jj < 4; ++jj) {
                float p = __expf(sv[t][jj] - m_new);
                sv[t][jj] = p;
                rsum += p;
            }
        rsum += __shfl_xor(rsum, 16);
        rsum += __shfl_xor(rsum, 32);
        l_run = l_run * corr + rsum;
        m_run = m_new;

        #pragma unroll
        for (int jj = 0; jj < 4; ++jj) {
            float c = __shfl(corr, kq*20 + jj);
            #pragma unroll
            for (int nt = 0; nt < 4; ++nt) oacc[nt][jj] *= c;
        }

        #pragma unroll
        for (int t = 0; t < 4; ++t) {
            unsigned pk0 = (unsigned)f2bf(sv[t][0]) | ((unsigned)f2bf(sv[t][1]) << 16);
            unsigned pk1 = (unsigned)f2bf(sv[t][2]) | ((unsigned)f2bf(sv[t][3]) << 16);
            unsigned off = ((unsigned)(lr*128 + t*32 + kq*8)) ^ (((unsigned)lr&7u)<<4);
            *(uint2*)(P_lds[w] + off) = make_uint2(pk0, pk1);
        }

        #pragma unroll
        for (int ks = 0; ks < 2; ++ks) {
            bf16x8 pa = *(const bf16x8*)(P_lds[w] +
                ((unsigned)(lr*128 + ((ks*64 + kq*16) ^ ((lr&7)<<4)))));
            #pragma unroll
            for (int nt = 0; nt < 4; ++nt) {
                int row = nt*16 + lr;
                bf16x8 vf = *(const bf16x8*)(VT_lds[cur] + row*128 + ((ks*64 + kq*16) ^ ((lr&7)<<4)));
                oacc[nt] = __builtin_amdgcn_mfma_f32_16x16x32_bf16(pa, vf, oacc[nt], 0,0,0);
            }
        }
        __syncthreads();   // drains next-tile stage loads; buffer-swap safety
    }

    #pragma unroll
    for (int jj = 0; jj < 4; ++jj) {
        float li = __shfl(l_run, kq*20 + jj);
        int qg = q0 + w*16 + kq*4 + jj;
        #pragma unroll
        for (int nt = 0; nt < 4; ++nt)
            y[(size_t)(b*TT + qg)*DM + h*64 + nt*16 + lr] =
                __float2bfloat16(oacc[nt][jj] / li);
    }
}

// ---------------- loss: single-pass online logsumexp, float4 loads ----------------
__global__ void zero_acc_kernel(float* p) { p[threadIdx.x] = 0.f; }

__global__ __launch_bounds__(256) void loss_kernel(const float* __restrict__ logits,
                                                   const int* __restrict__ targets,
                                                   float* __restrict__ acc) {
    int row = blockIdx.x;
    int tid = threadIdx.x;
    const float* lr = logits + (size_t)row * VOC;
    float m = -INFINITY, s = 0.f;
    // VOC = 50257 = 12564*4 + 1
    for (int c4 = tid; c4 < 12564; c4 += 256) {
        float4 v = ((const float4*)lr)[c4];
        float vm = fmaxf(fmaxf(v.x, v.y), fmaxf(v.z, v.w));
        if (vm > m) { s *= __expf(m - vm); m = vm; }
        s += __expf(v.x - m) + __expf(v.y - m) + __expf(v.z - m) + __expf(v.w - m);
    }
    if (tid == 0) {
        float v = lr[VOC - 1];
        if (v > m) { s *= __expf(m - v); m = v; }
        s += __expf(v - m);
    }
    __shared__ float rm[256], rs[256];
    rm[tid] = m; rs[tid] = s; __syncthreads();
    for (int off = 128; off > 0; off >>= 1) {
        if (tid < off) {
            float m2 = rm[tid+off], s2 = rs[tid+off];
            float M = fmaxf(rm[tid], m2);
            rs[tid] = rs[tid]*__expf(rm[tid]-M) + s2*__expf(m2-M);
            rm[tid] = M;
        }
        __syncthreads();
    }
    if (tid == 0) {
        int tgt = targets[row];
        if (tgt >= 0) {
            float lse = logf(rs[0]) + rm[0];
            atomicAdd(&acc[0], lse - lr[tgt]);
            atomicAdd(&acc[1], 1.f);
        }
    }
}

__global__ void loss_final_kernel(const float* acc, float* out) {
    out[0] = acc[0] / acc[1];
}

// ---------------- launch ----------------
static inline TJob mkjob(const float* in, __hip_bfloat16* out, int R, int C, int tile0) {
    TJob j; j.in = in; j.out = out; j.R = R; j.C = C;
    j.cx = (C + 31)/32; j.tile0 = tile0;
    return j;
}

extern "C" void kernel_launch(void* const* d_in, const int* in_sizes, int n_in,
                              void* d_out, int out_size, void* d_ws, size_t ws_size,
                              hipStream_t stream) {
    const int*   idx     = (const int*)  d_in[0];
    const int*   targets = (const int*)  d_in[1];
    const float* wte     = (const float*)d_in[2];
    const float* wpe     = (const float*)d_in[3];
    const float* ln1_g   = (const float*)d_in[4];
    const float* ln1_b   = (const float*)d_in[5];
    const float* qkv_w   = (const float*)d_in[6];
    const float* qkv_b   = (const float*)d_in[7];
    const float* po_w    = (const float*)d_in[8];
    const float* po_b    = (const float*)d_in[9];
    const float* ln2_g   = (const float*)d_in[10];
    const float* ln2_b   = (const float*)d_in[11];
    const float* fc_w    = (const float*)d_in[12];
    const float* fc_b    = (const float*)d_in[13];
    const float* pr_w    = (const float*)d_in[14];
    const float* pr_b    = (const float*)d_in[15];
    const float* lnf_g   = (const float*)d_in[16];
    const float* lnf_b   = (const float*)d_in[17];
    const float* lm_w    = (const float*)d_in[18];

    float* logits = (float*)d_out;                 // [MR][VOC], loss appended

    char* p = (char*)d_ws;
    float* x = (float*)p;                 p += (size_t)MR*DM*4;
    __hip_bfloat16* h    = (__hip_bfloat16*)p; p += (size_t)MR*DM*2;
    __hip_bfloat16* qkvb = (__hip_bfloat16*)p; p += (size_t)MR*3*DM*2;
    __hip_bfloat16* yb   = (__hip_bfloat16*)p; p += (size_t)MR*DM*2;
    __hip_bfloat16* fb   = (__hip_bfloat16*)p; p += (size_t)MR*FF*2;
    __hip_bfloat16* vtb  = (__hip_bfloat16*)p; p += (size_t)BB*NH*64*TT*2;
    __hip_bfloat16* lm_wt  = (__hip_bfloat16*)p; p += (size_t)VOC*DM*2;
    __hip_bfloat16* qkv_wt = (__hip_bfloat16*)p; p += (size_t)3*DM*DM*2;
    __hip_bfloat16* po_wt  = (__hip_bfloat16*)p; p += (size_t)DM*DM*2;
    __hip_bfloat16* fc_wt  = (__hip_bfloat16*)p; p += (size_t)FF*DM*2;
    __hip_bfloat16* pr_wt  = (__hip_bfloat16*)p; p += (size_t)DM*FF*2;
    float* lacc = (float*)p;

    dim3 tpb(32, 8);

    embed_kernel<<<MR, 256, 0, stream>>>(idx, wte, wpe, x);

    {
        TJob j = mkjob(lm_w, lm_wt, DM, VOC, 0);
        int tiles = j.cx * ((DM+31)/32);
        trans1_kernel<<<tiles, tpb, 0, stream>>>(j);
    }

    for (int l = 0; l < NL; l++) {
        TJob j0 = mkjob(qkv_w + (size_t)l*DM*3*DM, qkv_wt, DM, 3*DM, 0);
        int t1 = j0.cx * 24;
        TJob j1 = mkjob(po_w + (size_t)l*DM*DM, po_wt, DM, DM, t1);
        int t2 = t1 + j1.cx * 24;
        TJob j2 = mkjob(fc_w + (size_t)l*DM*FF, fc_wt, DM, FF, t2);
        int t3 = t2 + j2.cx * 24;
        TJob j3 = mkjob(pr_w + (size_t)l*FF*DM, pr_wt, FF, DM, t3);
        int tot = t3 + j3.cx * 96;
        trans4_kernel<<<tot, tpb, 0, stream>>>(j0, j1, j2, j3);

        ln_kernel<<<MR/4, 256, 0, stream>>>(x, ln1_g + l*DM, ln1_b + l*DM, h);
        mfma_gemm_kernel<1,0><<<(3*DM/128)*(MR/128), 256, 0, stream>>>(
            h, qkv_wt, qkv_b + (size_t)l*3*DM, nullptr, qkvb, vtb, MR, 3*DM, DM);
        mfma_attn_kernel<<<BB*NH*(TT/64), 256, 0, stream>>>(qkvb, vtb, yb);
        mfma_gemm_kernel<2,1><<<(DM/128)*(MR/64), 256, 0, stream>>>(
            yb, po_wt, po_b + (size_t)l*DM, x, x, nullptr, MR, DM, DM);
        ln_kernel<<<MR/4, 256, 0, stream>>>(x, ln2_g + l*DM, ln2_b + l*DM, h);
        mfma_gemm_kernel<3,0><<<(FF/128)*(MR/128), 256, 0, stream>>>(
            h, fc_wt, fc_b + (size_t)l*FF, nullptr, fb, nullptr, MR, FF, DM);
        mfma_gemm_kernel<2,1><<<(DM/128)*(MR/64), 256, 0, stream>>>(
            fb, pr_wt, pr_b + (size_t)l*DM, x, x, nullptr, MR, DM, FF);
    }

    ln_kernel<<<MR/4, 256, 0, stream>>>(x, lnf_g, lnf_b, h);
    mfma_gemm_kernel<0,0><<<((VOC+127)/128)*(MR/128), 256, 0, stream>>>(
        h, lm_wt, nullptr, nullptr, logits, nullptr, MR, VOC, DM);

    zero_acc_kernel<<<1, 2, 0, stream>>>(lacc);
    loss_kernel<<<MR, 256, 0, stream>>>(logits, targets, lacc);
    loss_final_kernel<<<1, 1, 0, stream>>>(lacc, logits + (size_t)MR*VOC);
}